// Round 4
// baseline (455.785 us; speedup 1.0000x reference)
//
#include <hip/hip_runtime.h>
#include <hip/hip_bf16.h>

// Problem constants
#define BB   4
#define FF   9
#define MPP  100
#define PP   12000
#define CC   64
#define NYY  400
#define NXO  4
#define NPIL (BB * PP)              // 48000
#define OUTN (BB * CC * NYY * NXO)  // 409600
#define CNTN (BB * NYY * NXO)       // 6400

// ws layout (byte offsets)
#define WS_MAXBUF 0
#define WS_CNT    (OUTN * 4)
#define WS_BIAS1  (WS_CNT + CNTN * 4)      // 64 fp32
#define WS_BIAS2  (WS_BIAS1 + 256)         // 64 fp32
#define WS_W1PB   (WS_BIAS2 + 256)         // 64x16 bf16 (s1-folded, k-slot mapped)
#define WS_W2PB   (WS_W1PB + 2048)         // 64x64 bf16 (s2-folded)

typedef __attribute__((ext_vector_type(8)))  short short8;   // 8 bf16 = 4 VGPRs
typedef __attribute__((ext_vector_type(16))) float float16;  // MFMA 32x32 acc

__device__ __forceinline__ short f2bf(float v) {
    __hip_bfloat16 h = __float2bfloat16(v);
    short s; __builtin_memcpy(&s, &h, 2); return s;
}
// order-preserving fp32 <-> int key (self-inverse XOR form)
__device__ __forceinline__ int fkey(float v) {
    int b = __float_as_int(v);
    return b >= 0 ? b : (b ^ 0x7fffffff);
}
__device__ __forceinline__ float kinv(int k) {
    return __int_as_float(k >= 0 ? k : (k ^ 0x7fffffff));
}

// k-slot map for stage1 (must match pillar_kernel's B build):
//   s in [0,4)  -> f = s        (loaded by half0)
//   s in [8,13) -> f = s - 4    (loaded by half1)
//   else zero
__global__ void prep_kernel(const float* __restrict__ w1, const float* __restrict__ b1,
                            const float* __restrict__ g1, const float* __restrict__ be1,
                            const float* __restrict__ m1, const float* __restrict__ v1,
                            const float* __restrict__ w2, const float* __restrict__ b2,
                            const float* __restrict__ g2, const float* __restrict__ be2,
                            const float* __restrict__ m2, const float* __restrict__ v2,
                            char* __restrict__ ws)
{
    float* bias1 = (float*)(ws + WS_BIAS1);
    float* bias2 = (float*)(ws + WS_BIAS2);
    short* w1pb  = (short*)(ws + WS_W1PB);
    short* w2pb  = (short*)(ws + WS_W2PB);
    const int t = threadIdx.x;   // 256
    if (t < 64) {
        const float s1 = g1[t] * rsqrtf(v1[t] + 1e-3f);
        bias1[t] = s1 * b1[t] + (be1[t] - m1[t] * s1);
        #pragma unroll
        for (int s = 0; s < 16; ++s) {
            const int f = (s < 4) ? s : ((s >= 8 && s < 13) ? s - 4 : -1);
            w1pb[t * 16 + s] = (f >= 0) ? f2bf(s1 * w1[t * 9 + f]) : (short)0;
        }
        const float s2 = g2[t] * rsqrtf(v2[t] + 1e-3f);
        bias2[t] = s2 * b2[t] + (be2[t] - m2[t] * s2);
    }
    for (int i = t; i < CC * CC; i += 256) {
        const int d = i >> 6;
        const float s2 = g2[d] * rsqrtf(v2[d] + 1e-3f);
        w2pb[i] = f2bf(s2 * w2[i]);
    }
}

// Block = 256 threads (4 waves), 32 pillars. Wave wv handles mp in [25wv, 25wv+25).
// Stage1: z' = (s1*w1) . x via mfma_32x32x16_bf16, running fp32 max in 32 regs;
// cross-wave merge via LDS atomicMax on order-int keys. feat = relu(max+bias1).
// Stage2 (waves 0-1): K=64 MFMA chain with s2-folded w2; scatter-max (>=0 fp32
// bits as uint) into pooled grid + per-window occupancy count.
__global__ __launch_bounds__(256, 6) void pillar_kernel(
    const float* __restrict__ x, const int* __restrict__ coords,
    const char* __restrict__ ws_ro,
    unsigned int* __restrict__ maxbuf, int* __restrict__ cnt)
{
    __shared__ int   red[CC * 32];        // ordered-int z-max, 8 KB
    __shared__ short featbT[32 * 72];     // bf16 feat [p][c], stride 72 (16B-aligned)

    const float* bias1 = (const float*)(ws_ro + WS_BIAS1);
    const float* bias2 = (const float*)(ws_ro + WS_BIAS2);
    const short* w1pb  = (const short*)(ws_ro + WS_W1PB);
    const short* w2pb  = (const short*)(ws_ro + WS_W2PB);

    const int t    = threadIdx.x;
    const int lane = t & 63;
    const int wv   = t >> 6;          // 0..3
    const int half = lane >> 5;       // k-group
    const int pcol = lane & 31;       // pillar column (n) / row (m)
    const int v0   = blockIdx.x * 32; // never straddles a batch (12000 % 32 == 0)
    const int b    = v0 / PP;
    const int p0   = v0 - b * PP;

    // init reduction buffer
    #pragma unroll
    for (int i = 0; i < 8; ++i) red[i * 256 + t] = (int)0x80000000;

    // A fragments: w1' rows (k-slot mapped) for ch pcol and pcol+32
    const short8 a0 = *(const short8*)(w1pb + pcol * 16 + half * 8);
    const short8 a1 = *(const short8*)(w1pb + (pcol + 32) * 16 + half * 8);

    float16 vmx0, vmx1;
    #pragma unroll
    for (int r = 0; r < 16; ++r) { vmx0[r] = -3.0e38f; vmx1[r] = -3.0e38f; }

    __syncthreads();   // red init visible before atomics

    // x[b][f][mp][p]; this lane's f-base: half0 -> f=0.., half1 -> f=4..
    const float* q = x + (size_t)b * (FF * MPP * PP)
                       + (size_t)(wv * 25) * PP
                       + (size_t)half * (4 * MPP * PP)
                       + p0 + pcol;
    #pragma unroll 2
    for (int mp = 0; mp < 25; ++mp) {
        float xv0 = q[0];
        float xv1 = q[(size_t)1 * MPP * PP];
        float xv2 = q[(size_t)2 * MPP * PP];
        float xv3 = q[(size_t)3 * MPP * PP];
        float xv4 = q[(size_t)4 * MPP * PP];   // half0: f=4 (dup, discarded); half1: f=8
        xv4 = half ? xv4 : 0.0f;
        short8 bf = (short8)0;
        bf[0] = f2bf(xv0); bf[1] = f2bf(xv1); bf[2] = f2bf(xv2); bf[3] = f2bf(xv3);
        bf[4] = f2bf(xv4);
        const float16 z0 = __builtin_amdgcn_mfma_f32_32x32x16_bf16(a0, bf, (float16)0.f, 0, 0, 0);
        const float16 z1 = __builtin_amdgcn_mfma_f32_32x32x16_bf16(a1, bf, (float16)0.f, 0, 0, 0);
        #pragma unroll
        for (int r = 0; r < 16; ++r) {
            vmx0[r] = fmaxf(vmx0[r], z0[r]);
            vmx1[r] = fmaxf(vmx1[r], z1[r]);
        }
        q += PP;
    }

    // merge: D layout col=lane&31, row=(r&3)+8*(r>>2)+4*(lane>>5)
    #pragma unroll
    for (int r = 0; r < 16; ++r) {
        const int ch = (r & 3) + 8 * (r >> 2) + 4 * half;
        atomicMax(&red[ch * 32 + pcol],        fkey(vmx0[r]));
        atomicMax(&red[(ch + 32) * 32 + pcol], fkey(vmx1[r]));
    }
    __syncthreads();

    // feat = relu(max + bias1) -> bf16, transposed [p][c]
    {
        const int p  = t & 31;
        const int cg = t >> 5;      // 0..7, 8 channels each
        #pragma unroll
        for (int j = 0; j < 8; ++j) {
            const int c = cg * 8 + j;
            const float m = kinv(red[c * 32 + p]);
            featbT[p * 72 + c] = f2bf(fmaxf(0.f, m + bias1[c]));
        }
    }
    __syncthreads();

    // Stage2 on waves 0-1: wave wv computes d = wv*32..+31, K=64 in 4 chunks
    if (wv < 2) {
        const short* wrow = w2pb + (wv * 32 + pcol) * 64 + half * 8;
        const short8 wa0 = *(const short8*)(wrow +  0);
        const short8 wa1 = *(const short8*)(wrow + 16);
        const short8 wa2 = *(const short8*)(wrow + 32);
        const short8 wa3 = *(const short8*)(wrow + 48);
        const short* frow = &featbT[pcol * 72 + half * 8];
        const short8 fb0 = *(const short8*)(frow +  0);
        const short8 fb1 = *(const short8*)(frow + 16);
        const short8 fb2 = *(const short8*)(frow + 32);
        const short8 fb3 = *(const short8*)(frow + 48);

        float16 acc = (float16)0.f;
        acc = __builtin_amdgcn_mfma_f32_32x32x16_bf16(wa0, fb0, acc, 0, 0, 0);
        acc = __builtin_amdgcn_mfma_f32_32x32x16_bf16(wa1, fb1, acc, 0, 0, 0);
        acc = __builtin_amdgcn_mfma_f32_32x32x16_bf16(wa2, fb2, acc, 0, 0, 0);
        acc = __builtin_amdgcn_mfma_f32_32x32x16_bf16(wa3, fb3, acc, 0, 0, 0);

        const int* c4 = coords + (size_t)(v0 + pcol) * 4;
        const int cb = c4[0];
        const int cy = c4[2];
        const int xo = c4[3] / 100;
        const int base = ((cb * CC) * NYY + cy) * NXO + xo;
        #pragma unroll
        for (int r = 0; r < 16; ++r) {
            const int d = wv * 32 + (r & 3) + 8 * (r >> 2) + 4 * half;
            const float val = fmaxf(0.f, acc[r] + bias2[d]);
            atomicMax(&maxbuf[base + d * (NYY * NXO)], __float_as_uint(val));
        }
    }
    if (t < 32) {
        const int* c4 = coords + (size_t)(v0 + t) * 4;
        atomicAdd(&cnt[(c4[0] * NYY + c4[2]) * NXO + c4[3] / 100], 1);
    }
}

// out = max(maxbuf, zval[d] if the 100-wide window has at least one empty cell)
__global__ __launch_bounds__(256) void finalize_kernel(
    const unsigned int* __restrict__ maxbuf, const int* __restrict__ cnt,
    const float* __restrict__ b2, const float* __restrict__ g2,
    const float* __restrict__ be2, const float* __restrict__ m2,
    const float* __restrict__ v2, float* __restrict__ out)
{
    const int idx = blockIdx.x * 256 + threadIdx.x;   // < OUTN exact
    const int xo = idx & 3;
    const int tt = idx >> 2;
    const int y  = tt % NYY;
    const int bd = tt / NYY;
    const int d  = bd & 63;
    const int b  = bd >> 6;

    const float s2 = g2[d] * rsqrtf(v2[d] + 1e-3f);
    const float t2 = be2[d] - m2[d] * s2;
    const float zval = fmaxf(0.f, fmaf(s2, b2[d], t2));

    const float mv = __uint_as_float(maxbuf[idx]);
    const int   cv = cnt[(b * NYY + y) * NXO + xo];
    out[idx] = (cv >= 100) ? mv : fmaxf(mv, zval);
}

extern "C" void kernel_launch(void* const* d_in, const int* in_sizes, int n_in,
                              void* d_out, int out_size, void* d_ws, size_t ws_size,
                              hipStream_t stream) {
    const float* x   = (const float*)d_in[0];
    const int*   cds = (const int*)d_in[1];
    const float* w1  = (const float*)d_in[2];
    const float* b1  = (const float*)d_in[3];
    const float* g1  = (const float*)d_in[4];
    const float* be1 = (const float*)d_in[5];
    const float* m1  = (const float*)d_in[6];
    const float* v1  = (const float*)d_in[7];
    const float* w2  = (const float*)d_in[8];
    const float* b2  = (const float*)d_in[9];
    const float* g2  = (const float*)d_in[10];
    const float* be2 = (const float*)d_in[11];
    const float* m2  = (const float*)d_in[12];
    const float* v2  = (const float*)d_in[13];

    char* ws = (char*)d_ws;
    unsigned int* maxbuf = (unsigned int*)(ws + WS_MAXBUF);
    int*          cnt    = (int*)(ws + WS_CNT);

    // zero maxbuf+cnt (uint 0 == fp32 0.0f, identity for >=0 max-scatter)
    hipMemsetAsync(ws, 0, (size_t)WS_BIAS1, stream);

    prep_kernel<<<1, 256, 0, stream>>>(w1, b1, g1, be1, m1, v1,
                                       w2, b2, g2, be2, m2, v2, ws);

    pillar_kernel<<<NPIL / 32, 256, 0, stream>>>(x, cds, ws, maxbuf, cnt);

    finalize_kernel<<<OUTN / 256, 256, 0, stream>>>(
        maxbuf, cnt, b2, g2, be2, m2, v2, (float*)d_out);
}